// Round 9
// baseline (137.924 us; speedup 1.0000x reference)
//
#include <hip/hip_runtime.h>
#include <hip/hip_fp16.h>

#define NB 32
#define NP 4096
#define NM 12
#define NW 9
#define NC 64          // IN_C == OUT_C == 64
#define PN_PAD 4097
#define KDIM (NW * NC)     // 576
#define NKS (KDIM / 16)    // 36 K-steps of the 32x32x16 MFMA
#define WROW 144           // words per p in w2 table (12 m * 12 slots)

// two-pass split of the K dimension (by w-group)
#define W0 5               // pass-0 w's: 0..4  -> 320 cols, 20 K-steps
#define W1 4               // pass-1 w's: 5..8  -> 256 cols, 16 K-steps
#define KS0 (W0 * 4)       // 20
#define AROW0 328          // 320 + 8 pad shorts (dword-stride mod 32 == 4, zero-conflict class)
#define AROW1 264          // 256 + 8 pad shorts (same residue class)

#define WSW_BYTES (KDIM * NC * 2)            // 73728 B  f16 swizzled weights
#define W2_OFFSET WSW_BYTES
#define W2_BYTES (NP * WROW * 4)             // 2359296 B  w2 half2-dup table
#define XB_OFFSET (W2_OFFSET + W2_BYTES)     // 2433024
#define XB_BYTES (NB * PN_PAD * NC * 2)      // 16781312 B  f16 x
#define WS_NEED ((size_t)XB_OFFSET + XB_BYTES)

typedef __attribute__((ext_vector_type(8))) _Float16 f16x8;
typedef __attribute__((ext_vector_type(2))) float float2v;
typedef __attribute__((ext_vector_type(4))) float float4v;
typedef __attribute__((ext_vector_type(16))) float float16v;

__device__ __forceinline__ __half2 u2h(unsigned u) {
    union { unsigned u; __half2 h; } v; v.u = u; return v.h;
}
__device__ __forceinline__ unsigned h2u(__half2 h) {
    union { __half2 h; unsigned u; } v; v.h = h; return v.u;
}

// f32 -> f16 bits (RNE via v_cvt_f16_f32)
__device__ __forceinline__ unsigned f32_to_f16u(float f) {
    return __half_as_ushort(__float2half(f));
}

// Pack float4 -> 4 f16 (RNE)
__device__ __forceinline__ uint2 pack_f16x4(float4v v) {
    unsigned h0 = f32_to_f16u(v[0]), h1 = f32_to_f16u(v[1]);
    unsigned h2 = f32_to_f16u(v[2]), h3 = f32_to_f16u(v[3]);
    uint2 r; r.x = h0 | (h1 << 16); r.y = h2 | (h3 << 16); return r;
}

// Pack two float2 (lo = ch0,1 / hi = ch2,3) -> 4 f16 (fallback path)
__device__ __forceinline__ uint2 pack_f16x4_2(float2v lo, float2v hi) {
    unsigned h0 = f32_to_f16u(lo[0]), h1 = f32_to_f16u(lo[1]);
    unsigned h2 = f32_to_f16u(hi[0]), h3 = f32_to_f16u(hi[1]);
    uint2 r; r.x = h0 | (h1 << 16); r.y = h2 | (h3 << 16); return r;
}

// Fused prep (verified R8 version, unchanged):
//  (a) weights fp32 -> f16 in 32x32x16 MFMA B-fragment order
//  (b) w2u[pm*12 + w] = dup_half2(ww[pm,w] * mask[pm])  (slots 9..11 zeroed)
//  (c) (DOX) x fp32 -> f16 rows
template<int DOX>
__global__ void prep_all(const float* __restrict__ w,
                         const float* __restrict__ ww,
                         const float* __restrict__ mask,
                         const float* __restrict__ x,
                         unsigned short* __restrict__ wsw,
                         unsigned* __restrict__ w2u,
                         unsigned short* __restrict__ xb) {
    int idx = blockIdx.x * 256 + threadIdx.x;
    if (idx < KDIM * NC) {
        int j    = idx & 7;
        int lane = (idx >> 3) & 63;
        int f    = idx >> 9;       // 0..71  = ks*2 + nt2
        int nt2  = f & 1;
        int ks   = f >> 1;         // 0..35
        int k = ks * 16 + ((lane >> 5) * 8) + j;   // k = w*64 + i
        int n = nt2 * 32 + (lane & 31);            // n = o
        int wi = k >> 6;
        int ii = k & 63;
        wsw[idx] = (unsigned short)f32_to_f16u(w[wi * (NC * NC) + n * NC + ii]);
    }
    if (idx < NP * NM * 12) {
        int wq = idx % 12;
        int pm = idx / 12;       // p*12 + m
        float v = 0.f;
        if (wq < NW) v = ww[pm * NW + wq] * mask[pm];
        unsigned hv = f32_to_f16u(v);
        w2u[idx] = hv | (hv << 16);        // duplicated half2
    }
    if (DOX) {
        const int n4 = NB * PN_PAD * NC / 4;  // 2097664
        if (idx < n4) {
            const float4v* x4 = (const float4v*)x;
            ((uint2*)xb)[idx] = pack_f16x4(x4[idx]);
        }
    }
}

// One block (512 threads) per p.  [R8 arithmetic; two-pass K to halve LDS]
//   gathers (12 x uint2, kept in regs across both passes)
//   pass0 FMA (w 0..4) -> A[32][328]          ; bar (A0 ready)
//   waves 0-1: MFMA ks 0..19   | waves 2-7: pass1 FMA compute (regs only)
//   bar (A0 consumed) ; write A1 (w 5..8, stride 264) ; bar (A1 ready)
//   waves 0-1: MFMA ks 20..35, + bias, direct store (R1-proven form)
template<int F16X>
__global__ __launch_bounds__(512)
void conv_main(const float* __restrict__ x,            // used only when !F16X
               const unsigned short* __restrict__ xb,  // (32, 4097, 64) f16
               const unsigned short* __restrict__ wsw,
               const float* __restrict__ bias,
               const unsigned* __restrict__ w2u,
               const int* __restrict__ nid,
               float* __restrict__ out) {
    __shared__ __align__(16) unsigned short A[NB * AROW0];   // 20992 B

    const int p   = blockIdx.x;
    const int tid = threadIdx.x;
    const int i4  = tid & 15;     // 4-channel group within the 64-ch row
    const int b   = tid >> 4;     // 0..31
    const int lane = tid & 63;
    const int wid  = tid >> 6;    // 0..7
    const int col  = lane & 31;   // A row (= b) and C col within tile
    const int hf   = lane >> 5;

    const unsigned* w2p = w2u + p * WROW;
    const int* nidp = nid + p * NM;

    int nm[NM];
    #pragma unroll
    for (int m = 0; m < NM; ++m) nm[m] = nidp[m];  // uniform -> SGPRs

    // ---- gathers, once, kept in registers across both passes ----
    uint2   xv[NM];     // F16X path
    float4v xvf[NM];    // fp32 fallback
    if (F16X) {
        const uint2* xb2 = (const uint2*)xb;   // row = 16 uint2 (128 B)
        #pragma unroll
        for (int m = 0; m < NM; ++m)
            xv[m] = xb2[(b * PN_PAD + nm[m]) * 16 + i4];
    } else {
        const float4v* x4 = (const float4v*)x;
        #pragma unroll
        for (int m = 0; m < NM; ++m)
            xvf[m] = x4[(b * PN_PAD + nm[m]) * 16 + i4];
    }

    const f16x8* Bfrags = (const f16x8*)wsw;
    float16v acc = {0.f,0.f,0.f,0.f, 0.f,0.f,0.f,0.f,
                    0.f,0.f,0.f,0.f, 0.f,0.f,0.f,0.f};

    // ---- pass 0 FMA: w 0..4 ----
    if (F16X) {
        __half2 a0[W0], a1[W0];
        #pragma unroll
        for (int w = 0; w < W0; ++w) { a0[w] = u2h(0u); a1[w] = u2h(0u); }
        #pragma unroll
        for (int m = 0; m < NM; ++m) {
            const __half2 lo = u2h(xv[m].x);
            const __half2 hi = u2h(xv[m].y);
            #pragma unroll
            for (int w = 0; w < W0; ++w) {
                const __half2 wb = u2h(w2p[m * 12 + w]);  // uniform scalar load
                a0[w] = __hfma2(lo, wb, a0[w]);
                a1[w] = __hfma2(hi, wb, a1[w]);
            }
        }
        #pragma unroll
        for (int w = 0; w < W0; ++w) {
            uint2 st; st.x = h2u(a0[w]); st.y = h2u(a1[w]);
            *(uint2*)&A[b * AROW0 + w * 64 + i4 * 4] = st;
        }
    } else {
        float2v a0[W0], a1[W0];
        #pragma unroll
        for (int w = 0; w < W0; ++w) { a0[w] = (float2v){0.f,0.f}; a1[w] = (float2v){0.f,0.f}; }
        #pragma unroll
        for (int m = 0; m < NM; ++m) {
            const float2v lo = {xvf[m][0], xvf[m][1]};
            const float2v hi = {xvf[m][2], xvf[m][3]};
            #pragma unroll
            for (int w = 0; w < W0; ++w) {
                const float ws = __half2float(__ushort_as_half(
                    (unsigned short)(w2p[m * 12 + w] & 0xFFFFu)));
                a0[w] += lo * ws;
                a1[w] += hi * ws;
            }
        }
        #pragma unroll
        for (int w = 0; w < W0; ++w)
            *(uint2*)&A[b * AROW0 + w * 64 + i4 * 4] = pack_f16x4_2(a0[w], a1[w]);
    }
    __syncthreads();   // A0 ready

    // ---- waves 0-1: MFMA over pass-0 K-range ----
    if (wid < 2) {
        #pragma unroll
        for (int ks = 0; ks < KS0; ++ks) {
            f16x8 bfrag = Bfrags[(ks * 2 + wid) * 64 + lane];
            const f16x8 a = *(const f16x8*)&A[col * AROW0 + ks * 16 + hf * 8];
            acc = __builtin_amdgcn_mfma_f32_32x32x16_f16(a, bfrag, acc, 0, 0, 0);
        }
    }

    // ---- pass 1 FMA compute (register-only; overlaps waves 0-1 MFMA) ----
    uint2 st1[W1];
    if (F16X) {
        __half2 b0[W1], b1[W1];
        #pragma unroll
        for (int w = 0; w < W1; ++w) { b0[w] = u2h(0u); b1[w] = u2h(0u); }
        #pragma unroll
        for (int m = 0; m < NM; ++m) {
            const __half2 lo = u2h(xv[m].x);
            const __half2 hi = u2h(xv[m].y);
            #pragma unroll
            for (int w = 0; w < W1; ++w) {
                const __half2 wb = u2h(w2p[m * 12 + (w + W0)]);
                b0[w] = __hfma2(lo, wb, b0[w]);
                b1[w] = __hfma2(hi, wb, b1[w]);
            }
        }
        #pragma unroll
        for (int w = 0; w < W1; ++w) { st1[w].x = h2u(b0[w]); st1[w].y = h2u(b1[w]); }
    } else {
        float2v b0[W1], b1[W1];
        #pragma unroll
        for (int w = 0; w < W1; ++w) { b0[w] = (float2v){0.f,0.f}; b1[w] = (float2v){0.f,0.f}; }
        #pragma unroll
        for (int m = 0; m < NM; ++m) {
            const float2v lo = {xvf[m][0], xvf[m][1]};
            const float2v hi = {xvf[m][2], xvf[m][3]};
            #pragma unroll
            for (int w = 0; w < W1; ++w) {
                const float ws = __half2float(__ushort_as_half(
                    (unsigned short)(w2p[m * 12 + (w + W0)] & 0xFFFFu)));
                b0[w] += lo * ws;
                b1[w] += hi * ws;
            }
        }
        #pragma unroll
        for (int w = 0; w < W1; ++w) st1[w] = pack_f16x4_2(b0[w], b1[w]);
    }

    __syncthreads();   // A0 fully consumed (MFMA reads drained)

    #pragma unroll
    for (int w = 0; w < W1; ++w)
        *(uint2*)&A[b * AROW1 + w * 64 + i4 * 4] = st1[w];

    __syncthreads();   // A1 ready

    // ---- waves 0-1: MFMA over pass-1 K-range + direct store ----
    if (wid < 2) {
        #pragma unroll
        for (int ks = KS0; ks < NKS; ++ks) {
            f16x8 bfrag = Bfrags[(ks * 2 + wid) * 64 + lane];
            const f16x8 a = *(const f16x8*)&A[col * AROW1 + (ks - KS0) * 16 + hf * 8];
            acc = __builtin_amdgcn_mfma_f32_32x32x16_f16(a, bfrag, acc, 0, 0, 0);
        }

        const int o = wid * 32 + col;
        const float bv = bias[o];
        // C/D layout (HW-verified): col=lane&31, row=(reg&3)+8*(reg>>2)+4*(lane>>5)
        #pragma unroll
        for (int reg = 0; reg < 16; ++reg) {
            const int br = (reg & 3) + 8 * (reg >> 2) + 4 * hf;
            out[(br * NP + p) * NC + o] = acc[reg] + bv;
        }
    }
}

extern "C" void kernel_launch(void* const* d_in, const int* in_sizes, int n_in,
                              void* d_out, int out_size, void* d_ws, size_t ws_size,
                              hipStream_t stream) {
    const float* x    = (const float*)d_in[0];
    const float* w    = (const float*)d_in[1];
    const float* bias = (const float*)d_in[2];
    const float* ww   = (const float*)d_in[3];
    const int*   nid  = (const int*)d_in[4];
    const float* mask = (const float*)d_in[5];
    float* out = (float*)d_out;
    unsigned short* wsw = (unsigned short*)d_ws;
    unsigned* w2u = (unsigned*)((char*)d_ws + W2_OFFSET);
    unsigned short* xb = (unsigned short*)((char*)d_ws + XB_OFFSET);

    if (ws_size >= WS_NEED) {
        const int n4 = NB * PN_PAD * NC / 4;  // 2097664 — sizes the fused prep grid
        hipLaunchKernelGGL(prep_all<1>, dim3((n4 + 255) / 256), dim3(256), 0, stream,
                           w, ww, mask, x, wsw, w2u, xb);
        hipLaunchKernelGGL(conv_main<1>, dim3(NP), dim3(512), 0, stream,
                           x, xb, wsw, bias, w2u, nid, out);
    } else {
        const int prep_elems = NP * NM * 12;  // 589824 covers wsw + w2 jobs
        hipLaunchKernelGGL(prep_all<0>, dim3((prep_elems + 255) / 256), dim3(256), 0, stream,
                           w, ww, mask, x, wsw, w2u, xb);
        hipLaunchKernelGGL(conv_main<0>, dim3(NP), dim3(512), 0, stream,
                           x, xb, wsw, bias, w2u, nid, out);
    }
}

// Round 10
// 124.478 us; speedup vs baseline: 1.1080x; 1.1080x over previous
//
#include <hip/hip_runtime.h>
#include <hip/hip_fp16.h>

#define NB 32
#define NP 4096
#define NM 12
#define NW 9
#define NC 64          // IN_C == OUT_C == 64
#define PN_PAD 4097
#define KDIM (NW * NC)     // 576
#define NKS (KDIM / 16)    // 36 K-steps of the 32x32x16 MFMA
#define KCH 4              // K-chunks in phase 2
#define KSPC (NKS / KCH)   // 9 K-steps per chunk
#define AROW 584           // 576 + 8 pad shorts (16B-aligned rows)
#define WROW 144           // words per p in w2 table (12 m * 12 slots)

#define WSW_BYTES (KDIM * NC * 2)            // 73728 B  f16 swizzled weights
#define W2_OFFSET WSW_BYTES
#define W2_BYTES (NP * WROW * 4)             // 2359296 B  w2 half2-dup table
#define XB_OFFSET (W2_OFFSET + W2_BYTES)     // 2433024
#define XB_BYTES (NB * PN_PAD * NC * 2)      // 16781312 B  f16 x
#define WS_NEED ((size_t)XB_OFFSET + XB_BYTES)

typedef __attribute__((ext_vector_type(8))) _Float16 f16x8;
typedef __attribute__((ext_vector_type(2))) float float2v;
typedef __attribute__((ext_vector_type(4))) float float4v;
typedef __attribute__((ext_vector_type(16))) float float16v;

__device__ __forceinline__ __half2 u2h(unsigned u) {
    union { unsigned u; __half2 h; } v; v.u = u; return v.h;
}
__device__ __forceinline__ unsigned h2u(__half2 h) {
    union { __half2 h; unsigned u; } v; v.h = h; return v.u;
}

// f32 -> f16 bits (RNE via v_cvt_f16_f32)
__device__ __forceinline__ unsigned f32_to_f16u(float f) {
    return __half_as_ushort(__float2half(f));
}

// Pack float4 -> 4 f16 (RNE)
__device__ __forceinline__ uint2 pack_f16x4(float4v v) {
    unsigned h0 = f32_to_f16u(v[0]), h1 = f32_to_f16u(v[1]);
    unsigned h2 = f32_to_f16u(v[2]), h3 = f32_to_f16u(v[3]);
    uint2 r; r.x = h0 | (h1 << 16); r.y = h2 | (h3 << 16); return r;
}

// Pack two float2 (lo = ch0,1 / hi = ch2,3) -> 4 f16 (fallback path)
__device__ __forceinline__ uint2 pack_f16x4_2(float2v lo, float2v hi) {
    unsigned h0 = f32_to_f16u(lo[0]), h1 = f32_to_f16u(lo[1]);
    unsigned h2 = f32_to_f16u(hi[0]), h3 = f32_to_f16u(hi[1]);
    uint2 r; r.x = h0 | (h1 << 16); r.y = h2 | (h3 << 16); return r;
}

// Fused prep (verified R8 version, unchanged):
//  (a) weights fp32 -> f16 in 32x32x16 MFMA B-fragment order
//  (b) w2u[pm*12 + w] = dup_half2(ww[pm,w] * mask[pm])  (slots 9..11 zeroed)
//  (c) (DOX) x fp32 -> f16 rows
template<int DOX>
__global__ void prep_all(const float* __restrict__ w,
                         const float* __restrict__ ww,
                         const float* __restrict__ mask,
                         const float* __restrict__ x,
                         unsigned short* __restrict__ wsw,
                         unsigned* __restrict__ w2u,
                         unsigned short* __restrict__ xb) {
    int idx = blockIdx.x * 256 + threadIdx.x;
    if (idx < KDIM * NC) {
        int j    = idx & 7;
        int lane = (idx >> 3) & 63;
        int f    = idx >> 9;       // 0..71  = ks*2 + nt2
        int nt2  = f & 1;
        int ks   = f >> 1;         // 0..35
        int k = ks * 16 + ((lane >> 5) * 8) + j;   // k = w*64 + i
        int n = nt2 * 32 + (lane & 31);            // n = o
        int wi = k >> 6;
        int ii = k & 63;
        wsw[idx] = (unsigned short)f32_to_f16u(w[wi * (NC * NC) + n * NC + ii]);
    }
    if (idx < NP * NM * 12) {
        int wq = idx % 12;
        int pm = idx / 12;       // p*12 + m
        float v = 0.f;
        if (wq < NW) v = ww[pm * NW + wq] * mask[pm];
        unsigned hv = f32_to_f16u(v);
        w2u[idx] = hv | (hv << 16);        // duplicated half2
    }
    if (DOX) {
        const int n4 = NB * PN_PAD * NC / 4;  // 2097664
        if (idx < n4) {
            const float4v* x4 = (const float4v*)x;
            ((uint2*)xb)[idx] = pack_f16x4(x4[idx]);
        }
    }
}

// One block (512 threads) per p.  [R8 champion + phase-2 operand prefetch]
// Entry: each wave prefetches its 9 wsw B-fragments + bias scalars into regs
//   (independent of gathers; latency hides under phase-1's 216 hfma2).
// Phase 1: t[b, w*64+i] (32 x 576) f16 acc via v_pk_fma_f16 (__hfma2).
// Phase 2: 8 waves, 32x32x16 f16 MFMA, 4-way K-split — pure LDS+MFMA now;
//   partials -> LDS (reusing A) -> reduce + bias + store.
template<int F16X>
__global__ __launch_bounds__(512)
void conv_main(const float* __restrict__ x,            // used only when !F16X
               const unsigned short* __restrict__ xb,  // (32, 4097, 64) f16
               const unsigned short* __restrict__ wsw,
               const float* __restrict__ bias,
               const unsigned* __restrict__ w2u,
               const int* __restrict__ nid,
               float* __restrict__ out) {
    __shared__ __align__(16) unsigned short A[NB * AROW];   // 37376 B (>= 32 KB partials)

    const int p = blockIdx.x;
    const int tid = threadIdx.x;

    // phase-2 thread mappings (needed for prefetch)
    const int lane = tid & 63;
    const int wid  = tid >> 6;     // 0..7
    const int nt   = wid & 1;      // N-tile (output channel half)
    const int kc   = wid >> 1;     // K-chunk 0..3
    const int col  = lane & 31;    // A row (= b) and C col within tile
    const int hf   = lane >> 5;
    // reduce mapping
    const int rc  = tid & 31;
    const int rg  = (tid >> 5) & 7;
    const int t2  = tid >> 8;      // which N-tile

    // ---- prefetch phase-2 operands (L2-hot, independent of gathers) ----
    const f16x8* Bfrags = (const f16x8*)wsw;
    f16x8 bf[KSPC];
    #pragma unroll
    for (int s = 0; s < KSPC; ++s)
        bf[s] = Bfrags[((kc * KSPC + s) * 2 + nt) * 64 + lane];
    const float bvr = bias[t2 * 32 + rc];

    // ---- Phase 1 ----
    {
        const int i4 = tid & 15;   // 4-channel group within the 64-ch row
        const int b  = tid >> 4;   // 0..31
        const unsigned* w2p = w2u + p * WROW;
        const int* nidp = nid + p * NM;

        int nm[NM];
        #pragma unroll
        for (int m = 0; m < NM; ++m) nm[m] = nidp[m];  // uniform -> SGPRs

        if (F16X) {
            const uint2* xb2 = (const uint2*)xb;   // row = 16 uint2 (128 B)
            uint2 xv[NM];
            #pragma unroll
            for (int m = 0; m < NM; ++m)
                xv[m] = xb2[(b * PN_PAD + nm[m]) * 16 + i4];

            __half2 acc0[NW], acc1[NW];
            #pragma unroll
            for (int w = 0; w < NW; ++w) {
                acc0[w] = u2h(0u);
                acc1[w] = u2h(0u);
            }
            #pragma unroll
            for (int m = 0; m < NM; ++m) {
                const __half2 lo = u2h(xv[m].x);   // ch0,1
                const __half2 hi = u2h(xv[m].y);   // ch2,3
                #pragma unroll
                for (int w = 0; w < NW; ++w) {
                    const __half2 wb = u2h(w2p[m * 12 + w]);  // uniform scalar load
                    acc0[w] = __hfma2(lo, wb, acc0[w]);       // v_pk_fma_f16
                    acc1[w] = __hfma2(hi, wb, acc1[w]);
                }
            }
            #pragma unroll
            for (int w = 0; w < NW; ++w) {
                uint2 st; st.x = h2u(acc0[w]); st.y = h2u(acc1[w]);
                *(uint2*)&A[b * AROW + w * 64 + i4 * 4] = st;  // 4 f16, no pack
            }
        } else {
            // fallback: fp32 gather, fp32 accumulate, convert to f16 at store
            const float4v* x4 = (const float4v*)x;
            float4v xv[NM];
            #pragma unroll
            for (int m = 0; m < NM; ++m)
                xv[m] = x4[(b * PN_PAD + nm[m]) * 16 + i4];

            float2v acc0[NW], acc1[NW];
            #pragma unroll
            for (int w = 0; w < NW; ++w) {
                acc0[w] = (float2v){0.f, 0.f};
                acc1[w] = (float2v){0.f, 0.f};
            }
            #pragma unroll
            for (int m = 0; m < NM; ++m) {
                const float2v lo = {xv[m][0], xv[m][1]};
                const float2v hi = {xv[m][2], xv[m][3]};
                #pragma unroll
                for (int w = 0; w < NW; ++w) {
                    const float ws = __half2float(__ushort_as_half(
                        (unsigned short)(w2p[m * 12 + w] & 0xFFFFu)));
                    acc0[w] += lo * ws;
                    acc1[w] += hi * ws;
                }
            }
            #pragma unroll
            for (int w = 0; w < NW; ++w)
                *(uint2*)&A[b * AROW + w * 64 + i4 * 4] = pack_f16x4_2(acc0[w], acc1[w]);
        }
    }
    __syncthreads();

    // ---- Phase 2: 8 waves, 32x32x16 f16 MFMA (prefetched B), 4-way K-split ----
    {
        float16v acc = {0.f,0.f,0.f,0.f, 0.f,0.f,0.f,0.f,
                        0.f,0.f,0.f,0.f, 0.f,0.f,0.f,0.f};

        #pragma unroll
        for (int s = 0; s < KSPC; ++s) {
            const int ks = kc * KSPC + s;
            const f16x8 a = *(const f16x8*)&A[col * AROW + ks * 16 + hf * 8];
            acc = __builtin_amdgcn_mfma_f32_32x32x16_f16(a, bf[s], acc, 0, 0, 0);
        }
        __syncthreads();               // all A reads complete

        // partials into LDS (reuse A region): P[nt][kc][row(b)][col] f32 = 32 KB
        float* P = (float*)A;
        #pragma unroll
        for (int reg = 0; reg < 16; ++reg) {
            const int row = (reg & 3) + 8 * (reg >> 2) + 4 * hf;
            P[((nt * KCH + kc) * 32 + row) * 32 + col] = acc[reg];
        }
        __syncthreads();

        // reduce 4 partials + bias (preloaded), coalesced store
        #pragma unroll
        for (int rr = 0; rr < 4; ++rr) {
            const int r = rg * 4 + rr;  // = b
            const float s = P[((t2 * KCH + 0) * 32 + r) * 32 + rc]
                          + P[((t2 * KCH + 1) * 32 + r) * 32 + rc]
                          + P[((t2 * KCH + 2) * 32 + r) * 32 + rc]
                          + P[((t2 * KCH + 3) * 32 + r) * 32 + rc];
            out[(r * NP + p) * NC + (t2 * 32 + rc)] = s + bvr;
        }
    }
}

extern "C" void kernel_launch(void* const* d_in, const int* in_sizes, int n_in,
                              void* d_out, int out_size, void* d_ws, size_t ws_size,
                              hipStream_t stream) {
    const float* x    = (const float*)d_in[0];
    const float* w    = (const float*)d_in[1];
    const float* bias = (const float*)d_in[2];
    const float* ww   = (const float*)d_in[3];
    const int*   nid  = (const int*)d_in[4];
    const float* mask = (const float*)d_in[5];
    float* out = (float*)d_out;
    unsigned short* wsw = (unsigned short*)d_ws;
    unsigned* w2u = (unsigned*)((char*)d_ws + W2_OFFSET);
    unsigned short* xb = (unsigned short*)((char*)d_ws + XB_OFFSET);

    if (ws_size >= WS_NEED) {
        const int n4 = NB * PN_PAD * NC / 4;  // 2097664 — sizes the fused prep grid
        hipLaunchKernelGGL(prep_all<1>, dim3((n4 + 255) / 256), dim3(256), 0, stream,
                           w, ww, mask, x, wsw, w2u, xb);
        hipLaunchKernelGGL(conv_main<1>, dim3(NP), dim3(512), 0, stream,
                           x, xb, wsw, bias, w2u, nid, out);
    } else {
        const int prep_elems = NP * NM * 12;  // 589824 covers wsw + w2 jobs
        hipLaunchKernelGGL(prep_all<0>, dim3((prep_elems + 255) / 256), dim3(256), 0, stream,
                           w, ww, mask, x, wsw, w2u, xb);
        hipLaunchKernelGGL(conv_main<0>, dim3(NP), dim3(512), 0, stream,
                           x, xb, wsw, bias, w2u, nid, out);
    }
}